// Round 2
// baseline (94.753 us; speedup 1.0000x reference)
//
#include <hip/hip_runtime.h>

// AdderNet 2D: out[n,f,i,j] = -sum_{c,kh,kw} |xpad[n,c,i+kh,j+kw] - W[f,c,kh,kw]|
// x: [16,32,56,56] f32, W: [64,32,3,3] f32, out: [16,64,56,56] f32. PAD=1, STRIDE=1.
//
// Design: no LDS at all. W goes through the scalar pipe (wave-uniform s_load from a
// 16B-aligned transposed copy wpad[c][f][12] in ws); x via direct global loads with
// per-lane precomputed offsets (L1-resident; 9 loads per channel per wave).
// Wave = 8x8 spatial tile x 8 filters, acc[8] in VGPRs. Grid = 16*49*8 = 6272 waves.

#define H_   56
#define C_   32
#define F_   64
#define N_   16
#define HW_  (H_ * H_)     // 3136
#define FPW  8             // filters per wave
#define NFG  (F_ / FPW)    // 8 filter groups
#define NT   49            // 7x7 tiles of 8x8 per image
#define WPAD_ELTS (C_ * F_ * 12)   // 24576 floats = 96 KB in ws

__global__ __launch_bounds__(64)
void prep_w(const float* __restrict__ w, float* __restrict__ wpad) {
    int idx = blockIdx.x * 64 + threadIdx.x;
    if (idx >= WPAD_ELTS) return;
    int c   = idx / (F_ * 12);
    int rem = idx % (F_ * 12);
    int f   = rem / 12;
    int kk  = rem % 12;
    wpad[idx] = (kk < 9) ? w[f * (C_ * 9) + c * 9 + kk] : 0.0f;
}

__global__ __launch_bounds__(64)
void adder_main(const float* __restrict__ x,
                const float* __restrict__ wpad,
                float* __restrict__ out) {
    const int lane = threadIdx.x;
    const int lr = lane >> 3;          // 0..7 tile row
    const int lc = lane & 7;           // 0..7 tile col
    const int bid = blockIdx.x;
    const int fg = bid & (NFG - 1);    // filter group (fastest -> same-tile waves adjacent)
    const int t  = (bid >> 3) % NT;
    const int n  = bid / (NT * NFG);
    const int r0 = (t / 7) * 8;
    const int c0 = (t % 7) * 8;
    const int f0 = fg * FPW;

    // per-lane x offsets + zero-pad masks (computed once, outside the K loop)
    int   off[9];
    float msk[9];
    #pragma unroll
    for (int kh = 0; kh < 3; ++kh) {
        #pragma unroll
        for (int kw = 0; kw < 3; ++kw) {
            int rp = r0 + lr + kh - 1;
            int cp = c0 + lc + kw - 1;
            bool v = (rp >= 0 && rp < H_ && cp >= 0 && cp < H_);
            off[kh * 3 + kw] = v ? rp * H_ + cp : 0;   // clamp to safe addr
            msk[kh * 3 + kw] = v ? 1.0f : 0.0f;        // zero-pad contribution
        }
    }

    float acc[FPW];
    #pragma unroll
    for (int f = 0; f < FPW; ++f) acc[f] = 0.0f;

    const float* xb = x + n * C_ * HW_;

    #pragma unroll 2
    for (int c = 0; c < C_; ++c) {
        float xv[9];
        #pragma unroll
        for (int k = 0; k < 9; ++k)
            xv[k] = xb[c * HW_ + off[k]] * msk[k];     // 1 VMEM + 1 v_mul each

        const float* wp = wpad + (c * F_ + f0) * 12;   // wave-uniform -> s_load
        #pragma unroll
        for (int f = 0; f < FPW; ++f) {
            #pragma unroll
            for (int k = 0; k < 9; ++k)
                acc[f] += fabsf(xv[k] - wp[f * 12 + k]);  // v_sub + v_add(|.|) per step
        }
    }

    const int orow = r0 + lr, ocol = c0 + lc;
    #pragma unroll
    for (int f = 0; f < FPW; ++f)
        out[((n * F_ + f0 + f) * H_ + orow) * H_ + ocol] = -acc[f];
}

extern "C" void kernel_launch(void* const* d_in, const int* in_sizes, int n_in,
                              void* d_out, int out_size, void* d_ws, size_t ws_size,
                              hipStream_t stream) {
    const float* x = (const float*)d_in[0];
    const float* w = (const float*)d_in[1];
    float* out  = (float*)d_out;
    float* wpad = (float*)d_ws;   // 96 KB scratch

    prep_w<<<dim3((WPAD_ELTS + 63) / 64), dim3(64), 0, stream>>>(w, wpad);
    adder_main<<<dim3(N_ * NT * NFG), dim3(64), 0, stream>>>(x, wpad, out);
}

// Round 3
// 76.651 us; speedup vs baseline: 1.2362x; 1.2362x over previous
//
#include <hip/hip_runtime.h>
#include <stdint.h>
#include <stddef.h>

// AdderNet 2D: out[n,f,i,j] = -sum_{c,kh,kw} |xpad[n,c,i+kh,j+kw] - W[f,c,kh,kw]|
// x: [16,32,56,56] f32, W: [64,32,3,3] f32, out: [16,64,56,56] f32. PAD=1, STRIDE=1.
//
// Structure: wave = 1 output row (lane=col, 56 active) x 8 filters.
//  - x: 9 buffer_load_dword per channel from per-row SRDs (num_records=224);
//    hardware OOB-zero IS the zero-pad semantics (|0-w| terms included, matching ref).
//  - w: batched s_buffer_load (4x v16f32 + 1x v8f32) per channel from transposed
//    wq[c][fg][96] (384B-aligned) in ws -> scalar pipe, one lgkm wait per channel.
//  - Inner body: 8 filters x 9 k x (v_subrev + v_add with |.| modifier) = 144 VALU,
//    zero per-lane addressing/masking. Manual 2-deep pipeline on x loads.

#define N_   16
#define C_   32
#define H_   56
#define F_   64
#define HW_  3136
#define FPW  8
#define NFG  8
#define ROWB 224                       // bytes per x row
#define WQ_ELTS (C_ * NFG * 96)       // 24576 floats = 96 KB in ws

typedef int    int32x4 __attribute__((ext_vector_type(4)));
typedef float  f32x16  __attribute__((ext_vector_type(16)));
typedef float  f32x8   __attribute__((ext_vector_type(8)));

__device__ float  __buf_load_f32(int32x4 srsrc, int voffset, int soffset, int aux) __asm("llvm.amdgcn.raw.buffer.load.f32");
__device__ f32x16 __sbuf_load_v16(int32x4 srsrc, int soffset, int aux) __asm("llvm.amdgcn.s.buffer.load.v16f32");
__device__ f32x8  __sbuf_load_v8 (int32x4 srsrc, int soffset, int aux) __asm("llvm.amdgcn.s.buffer.load.v8f32");

__device__ inline int32x4 make_srd(const void* p, int bytes) {
    union { const void* p; uint32_t u[2]; } a; a.p = p;
    int32x4 r;
    r.x = (int)a.u[0];
    r.y = (int)a.u[1];        // VA < 2^48, high bits 0 -> stride field 0
    r.z = bytes;              // num_records (stride==0 -> bytes)
    r.w = 0x00020000;         // raw untyped dword
    return r;
}

// wq[(c*NFG+fg)*96 + fi*9 + kk] = W[(fg*8+fi)*288 + c*9 + kk], pad [72..95]=0
__global__ __launch_bounds__(64)
void prep_w(const float* __restrict__ w, float* __restrict__ wq) {
    int idx = blockIdx.x * 64 + threadIdx.x;
    if (idx >= WQ_ELTS) return;
    int slot = idx % 96;
    int cg   = idx / 96;          // c*NFG + fg
    int c    = cg / NFG;
    int fg   = cg % NFG;
    int fi   = slot / 9;
    int kk   = slot % 9;
    float v = 0.0f;
    if (slot < 72)
        v = w[((fg * 8 + fi) * C_ + c) * 9 + kk];
    wq[idx] = v;
}

__global__ __launch_bounds__(64)
void adder_main(const float* __restrict__ x,
                const float* __restrict__ wq,
                float* __restrict__ out) {
    const int lane = threadIdx.x;
    const int bid  = blockIdx.x;
    const int fg   = bid & (NFG - 1);
    const int bid2 = bid >> 3;
    const int row  = bid2 % H_;
    const int n    = bid2 / H_;
    const int f0   = fg * FPW;

    const int vA = (lane - 1) * 4;   // col j-1 (lane 0 -> 0xFFFFFFFC -> HW OOB zero)
    const int vB = lane * 4;         // col j   (+soffset 4 -> col j+1)

    const int nr0 = (row >= 1)      ? ROWB : 0;   // kh=0 row validity (wave-uniform)
    const int nr2 = (row <= H_ - 2) ? ROWB : 0;   // kh=2

    // base of x row (row-1) for this n; kh adds H_, channel adds HW_
    const float* xb = x + (size_t)n * C_ * HW_ + (ptrdiff_t)(row - 1) * H_;

    const int32x4 wsrd = make_srd(wq, WQ_ELTS * 4);
    const int wgbase = fg * 96 * 4;               // byte offset of this fg's chunk

    float acc[FPW];
#pragma unroll
    for (int f = 0; f < FPW; ++f) acc[f] = 0.0f;

    float xva[9], xvb[9];

    auto load_ch = [&](int c, float* v) {
        const float* b = xb + (size_t)c * HW_;
        int32x4 s0 = make_srd(b,          nr0);
        int32x4 s1 = make_srd(b + H_,     ROWB);
        int32x4 s2 = make_srd(b + 2 * H_, nr2);
        v[0] = __buf_load_f32(s0, vA, 0, 0);
        v[1] = __buf_load_f32(s0, vB, 0, 0);
        v[2] = __buf_load_f32(s0, vB, 4, 0);
        v[3] = __buf_load_f32(s1, vA, 0, 0);
        v[4] = __buf_load_f32(s1, vB, 0, 0);
        v[5] = __buf_load_f32(s1, vB, 4, 0);
        v[6] = __buf_load_f32(s2, vA, 0, 0);
        v[7] = __buf_load_f32(s2, vB, 0, 0);
        v[8] = __buf_load_f32(s2, vB, 4, 0);
    };

    auto compute = [&](int c, const float* cur) {
        const int wb = c * (NFG * 96 * 4) + wgbase;
        f32x16 w0 = __sbuf_load_v16(wsrd, wb,       0);
        f32x16 w1 = __sbuf_load_v16(wsrd, wb + 64,  0);
        f32x16 w2 = __sbuf_load_v16(wsrd, wb + 128, 0);
        f32x16 w3 = __sbuf_load_v16(wsrd, wb + 192, 0);
        f32x8  w4 = __sbuf_load_v8 (wsrd, wb + 256, 0);
#pragma unroll
        for (int f = 0; f < FPW; ++f) {
#pragma unroll
            for (int k = 0; k < 9; ++k) {
                const int i = f * 9 + k;
                const float wv = (i < 16) ? w0[i]
                               : (i < 32) ? w1[i - 16]
                               : (i < 48) ? w2[i - 32]
                               : (i < 64) ? w3[i - 48]
                               :            w4[i - 64];
                acc[f] += fabsf(cur[k] - wv);
            }
        }
    };

    load_ch(0, xva);
    for (int c = 0; c < C_; c += 2) {
        load_ch(c + 1, xvb);          // c+1 <= 31 always (C_ even)
        compute(c, xva);
        if (c + 2 < C_) load_ch(c + 2, xva);
        compute(c + 1, xvb);
    }

    if (lane < H_) {
#pragma unroll
        for (int f = 0; f < FPW; ++f)
            out[(size_t)(n * F_ + f0 + f) * HW_ + row * H_ + lane] = -acc[f];
    }
}

extern "C" void kernel_launch(void* const* d_in, const int* in_sizes, int n_in,
                              void* d_out, int out_size, void* d_ws, size_t ws_size,
                              hipStream_t stream) {
    const float* x = (const float*)d_in[0];
    const float* w = (const float*)d_in[1];
    float* out = (float*)d_out;
    float* wqp = (float*)d_ws;    // 96 KB scratch

    prep_w<<<dim3((WQ_ELTS + 63) / 64), dim3(64), 0, stream>>>(w, wqp);
    adder_main<<<dim3(N_ * H_ * NFG), dim3(64), 0, stream>>>(x, wqp, out);
}